// Round 7
// baseline (774.912 us; speedup 1.0000x reference)
//
#include <hip/hip_runtime.h>
#include <cstdint>
#include <cstddef>

// ---------------------------------------------------------------------------
// TreeModel: hierarchical bi-GRU (sentence + doc) + MLP head. Round 7:
//   - doc_gru_mfma v4: register double-buffered x prefetch (hides the 24
//     L2 gathers/step that dominated the serial path), single-pass f16 A
//     (h as f16-hi only: 48 MFMA/step, h_lo/rh_lo planes dropped).
//   - everything else unchanged from round 6.
// ---------------------------------------------------------------------------

typedef __attribute__((ext_vector_type(8))) short bf16x8;     // 8 bf16 = 4 VGPR
typedef __attribute__((ext_vector_type(8))) _Float16 f16x8;   // 8 f16  = 4 VGPR
typedef __attribute__((ext_vector_type(4))) float f32x4;      // C/D frag

__device__ __forceinline__ void split_bf16(float f, short& hi, short& lo) {
  unsigned u = __float_as_uint(f);
  unsigned rb = (u + 0x7FFFu + ((u >> 16) & 1u)) & 0xFFFF0000u;  // RNE
  hi = (short)(rb >> 16);
  float r = f - __uint_as_float(rb);
  unsigned ur = __float_as_uint(r);
  lo = (short)((ur + 0x7FFFu + ((ur >> 16) & 1u)) >> 16);
}

__device__ __forceinline__ float sigm(float x) { return 1.f / (1.f + __expf(-x)); }
__device__ __forceinline__ float tanh_fast(float x) {
  float e = __expf(2.f * x);
  return 1.f - 2.f / (e + 1.f);
}

// Build transposed, split-bf16 B for embProj: Bt[n][k], n in [0,768), k in [0,128)
__global__ void bt_prep(const float* __restrict__ sWg_f, const float* __restrict__ sWc_f,
                        const float* __restrict__ sWg_b, const float* __restrict__ sWc_b,
                        short* __restrict__ BtHi, short* __restrict__ BtLo) {
  int i = blockIdx.x * 256 + threadIdx.x;
  if (i >= 768 * 128) return;
  int n = i >> 7, k = i & 127;
  float f;
  if (n < 256) f = sWg_f[k * 256 + n];
  else if (n < 384) f = sWc_f[k * 128 + (n - 256)];
  else if (n < 640) f = sWg_b[k * 256 + (n - 384)];
  else f = sWc_b[k * 128 + (n - 640)];
  short hi, lo;
  split_bf16(f, hi, lo);
  BtHi[i] = hi;
  BtLo[i] = lo;
}

// Transposed split-bf16 planes of doc x-part weights: PdT[n][k], n in [0,1536),
// k in [0,256). n layout: [dWg_f 512 | dWc_f 256 | dWg_b 512 | dWc_b 256].
__global__ void packdt_prep(const float* __restrict__ dWg_f, const float* __restrict__ dWc_f,
                            const float* __restrict__ dWg_b, const float* __restrict__ dWc_b,
                            short* __restrict__ Hi, short* __restrict__ Lo) {
  int i = blockIdx.x * 256 + threadIdx.x;
  if (i >= 1536 * 256) return;
  int n = i >> 8, k = i & 255;
  float f;
  if (n < 512) f = dWg_f[k * 512 + n];
  else if (n < 768) f = dWc_f[k * 256 + (n - 512)];
  else if (n < 1280) f = dWg_b[k * 512 + (n - 768)];
  else f = dWc_b[k * 256 + (n - 1280)];
  short hi, lo;
  split_bf16(f, hi, lo);
  Hi[i] = hi;
  Lo[i] = lo;
}

// ---------------------------------------------------------------------------
// embProj[50000,768] = emb[50000,128] @ packS[128,768], MFMA 3-pass split-bf16.
// ---------------------------------------------------------------------------
__global__ __launch_bounds__(256, 1) void emb_gemm(
    const float* __restrict__ emb, const short* __restrict__ BtHi,
    const short* __restrict__ BtLo, float* __restrict__ C) {
  const int tid = threadIdx.x;
  const int w = tid >> 6, l = tid & 63, li = l & 15, g = l >> 4;
  const int m0 = blockIdx.x * 64;

  bf16x8 ahi[4][4], alo[4][4];
#pragma unroll
  for (int mt = 0; mt < 4; ++mt) {
    int row = m0 + 16 * mt + li;
    if (row > 49999) row = 49999;
    const float* ap = emb + (size_t)row * 128 + 8 * g;
#pragma unroll
    for (int kk = 0; kk < 4; ++kk) {
      float4 v0 = *(const float4*)(ap + 32 * kk);
      float4 v1 = *(const float4*)(ap + 32 * kk + 4);
      float vv[8] = {v0.x, v0.y, v0.z, v0.w, v1.x, v1.y, v1.z, v1.w};
#pragma unroll
      for (int e = 0; e < 8; ++e) {
        short hi, lo;
        split_bf16(vv[e], hi, lo);
        ahi[mt][kk][e] = hi;
        alo[mt][kk][e] = lo;
      }
    }
  }

  f32x4 acc[4][12];
#pragma unroll
  for (int mt = 0; mt < 4; ++mt)
#pragma unroll
    for (int nt = 0; nt < 12; ++nt) acc[mt][nt] = (f32x4){0.f, 0.f, 0.f, 0.f};

#pragma unroll
  for (int nt = 0; nt < 12; ++nt) {
    const int col = 192 * w + 16 * nt + li;
    const short* bh = BtHi + col * 128 + 8 * g;
    const short* bl = BtLo + col * 128 + 8 * g;
    bf16x8 bhi[4], blo[4];
#pragma unroll
    for (int kk = 0; kk < 4; ++kk) {
      bhi[kk] = *(const bf16x8*)(bh + 32 * kk);
      blo[kk] = *(const bf16x8*)(bl + 32 * kk);
    }
#pragma unroll
    for (int kk = 0; kk < 4; ++kk)
#pragma unroll
      for (int mt = 0; mt < 4; ++mt) {
        acc[mt][nt] = __builtin_amdgcn_mfma_f32_16x16x32_bf16(alo[mt][kk], bhi[kk], acc[mt][nt], 0, 0, 0);
        acc[mt][nt] = __builtin_amdgcn_mfma_f32_16x16x32_bf16(ahi[mt][kk], blo[kk], acc[mt][nt], 0, 0, 0);
        acc[mt][nt] = __builtin_amdgcn_mfma_f32_16x16x32_bf16(ahi[mt][kk], bhi[kk], acc[mt][nt], 0, 0, 0);
      }
  }

#pragma unroll
  for (int mt = 0; mt < 4; ++mt)
#pragma unroll
    for (int nt = 0; nt < 12; ++nt) {
      const int col = 192 * w + 16 * nt + li;
#pragma unroll
      for (int r = 0; r < 4; ++r) {
        int row = m0 + 16 * mt + 4 * g + r;
        if (row < 50000) C[(size_t)row * 768 + col] = acc[mt][nt][r];
      }
    }
}

// ---------------------------------------------------------------------------
// xprojD[2048,1536] = sent[2048,256] @ packD[256,1536], MFMA 3-pass split-bf16.
// ---------------------------------------------------------------------------
__global__ __launch_bounds__(256, 1) void xproj_gemm(
    const short* __restrict__ AHi, const short* __restrict__ ALo,
    const short* __restrict__ BtHi, const short* __restrict__ BtLo,
    float* __restrict__ C) {
  const int tid = threadIdx.x;
  const int w = tid >> 6, l = tid & 63, li = l & 15, g = l >> 4;
  const int m0 = blockIdx.x * 64;
  const int n0 = blockIdx.y * 512 + 128 * w;

  f32x4 acc[4][8];
#pragma unroll
  for (int mt = 0; mt < 4; ++mt)
#pragma unroll
    for (int nt = 0; nt < 8; ++nt) acc[mt][nt] = (f32x4){0.f, 0.f, 0.f, 0.f};

#pragma unroll
  for (int kk = 0; kk < 8; ++kk) {
    bf16x8 ah[4], al[4];
#pragma unroll
    for (int mt = 0; mt < 4; ++mt) {
      const int row = m0 + 16 * mt + li;
      ah[mt] = *(const bf16x8*)&AHi[(size_t)row * 256 + 32 * kk + 8 * g];
      al[mt] = *(const bf16x8*)&ALo[(size_t)row * 256 + 32 * kk + 8 * g];
    }
#pragma unroll
    for (int nt = 0; nt < 8; ++nt) {
      const int col = n0 + 16 * nt + li;
      bf16x8 bh = *(const bf16x8*)&BtHi[(size_t)col * 256 + 32 * kk + 8 * g];
      bf16x8 bl = *(const bf16x8*)&BtLo[(size_t)col * 256 + 32 * kk + 8 * g];
#pragma unroll
      for (int mt = 0; mt < 4; ++mt) {
        acc[mt][nt] = __builtin_amdgcn_mfma_f32_16x16x32_bf16(al[mt], bh, acc[mt][nt], 0, 0, 0);
        acc[mt][nt] = __builtin_amdgcn_mfma_f32_16x16x32_bf16(ah[mt], bl, acc[mt][nt], 0, 0, 0);
        acc[mt][nt] = __builtin_amdgcn_mfma_f32_16x16x32_bf16(ah[mt], bh, acc[mt][nt], 0, 0, 0);
      }
    }
  }

#pragma unroll
  for (int mt = 0; mt < 4; ++mt)
#pragma unroll
    for (int nt = 0; nt < 8; ++nt) {
      const int col = n0 + 16 * nt + li;
#pragma unroll
      for (int r = 0; r < 4; ++r) {
        int row = m0 + 16 * mt + 4 * g + r;
        C[(size_t)row * 1536 + col] = acc[mt][nt][r];
      }
    }
}

// ---------------------------------------------------------------------------
// Sentence GRU, MFMA (round 3 core). grid (128,2), block 256.
// ---------------------------------------------------------------------------
#define SENTS 16

__global__ __launch_bounds__(256, 1) void sent_gru(
    const int* __restrict__ X, const int* __restrict__ L,
    const float* __restrict__ embProj,
    const float* __restrict__ Wg_f, const float* __restrict__ bg_f,
    const float* __restrict__ Wc_f, const float* __restrict__ bc_f,
    const float* __restrict__ Wg_b, const float* __restrict__ bg_b,
    const float* __restrict__ Wc_b, const float* __restrict__ bc_b,
    short* __restrict__ sentHi, short* __restrict__ sentLo) {
  const int dir = blockIdx.y;
  const int g0 = blockIdx.x * SENTS;
  const int tid = threadIdx.x;
  const int w = tid >> 6, l = tid & 63;
  const int li = l & 15, g = l >> 4;
  const float* Wg = dir ? Wg_b : Wg_f;
  const float* Wc = dir ? Wc_b : Wc_f;
  const float* bgp = dir ? bg_b : bg_f;
  const float* bcp = dir ? bc_b : bc_f;

  __shared__ float xbuf[2][SENTS][384];
  __shared__ float h_f[SENTS][132];
  __shared__ float u_f[SENTS][132];
  alignas(16) __shared__ short h_hi[SENTS][136], h_lo[SENTS][136];
  alignas(16) __shared__ short rh_hi[SENTS][136], rh_lo[SENTS][136];
  __shared__ int wid[2][SENTS];
  __shared__ int len_s[SENTS];

  bf16x8 bgh[4][4], bgl[4][4];
  bf16x8 bch[2][4], bcl[2][4];
#pragma unroll
  for (int nt = 0; nt < 4; ++nt)
#pragma unroll
    for (int kk = 0; kk < 4; ++kk) {
      const float* base = Wg + (size_t)(128 + 32 * kk + 8 * g) * 256 + 64 * w + 16 * nt + li;
#pragma unroll
      for (int e = 0; e < 8; ++e) {
        short hi, lo;
        split_bf16(base[(size_t)e * 256], hi, lo);
        bgh[nt][kk][e] = hi; bgl[nt][kk][e] = lo;
      }
    }
#pragma unroll
  for (int ct = 0; ct < 2; ++ct)
#pragma unroll
    for (int kk = 0; kk < 4; ++kk) {
      const float* base = Wc + (size_t)(128 + 32 * kk + 8 * g) * 128 + 32 * w + 16 * ct + li;
#pragma unroll
      for (int e = 0; e < 8; ++e) {
        short hi, lo;
        split_bf16(base[(size_t)e * 128], hi, lo);
        bch[ct][kk][e] = hi; bcl[ct][kk][e] = lo;
      }
    }
  float bgj[4], bcj[2];
#pragma unroll
  for (int nt = 0; nt < 4; ++nt) bgj[nt] = bgp[64 * w + 16 * nt + li];
#pragma unroll
  for (int ct = 0; ct < 2; ++ct) bcj[ct] = bcp[32 * w + 16 * ct + li];

  if (tid < SENTS) {
    int ll = L[g0 + tid];
    len_s[tid] = ll;
    wid[0][tid] = X[(g0 + tid) * 64 + (dir ? (ll - 1) : 0)];
    wid[1][tid] = (1 < ll) ? X[(g0 + tid) * 64 + (dir ? (ll - 2) : 1)] : 0;
  }
  for (int q = tid; q < SENTS * 136; q += 256) {
    ((short*)h_hi)[q] = 0; ((short*)h_lo)[q] = 0;
  }
  for (int q = tid; q < SENTS * 132; q += 256) ((float*)h_f)[q] = 0.f;
  __syncthreads();

  int lens4[4];
#pragma unroll
  for (int r = 0; r < 4; ++r) lens4[r] = len_s[4 * g + r];
  int maxlen = 0;
#pragma unroll
  for (int m = 0; m < SENTS; ++m) maxlen = max(maxlen, len_s[m]);

  auto prefetch_x = [&](int t) {
    int b = t & 1;
#pragma unroll
    for (int c = 0; c < 6; ++c) {
      int q = tid + 256 * c;
      int m = q / 96, s = q - m * 96;
      const float* src = embProj + (size_t)wid[b][m] * 768 + dir * 384 + s * 4;
      float* dst = (float*)&xbuf[b][0][0] + q * 4;
      __builtin_amdgcn_global_load_lds(
          (const __attribute__((address_space(1))) void*)src,
          (__attribute__((address_space(3))) void*)dst, 16, 0, 0);
    }
  };

  prefetch_x(0);
  __syncthreads();

  for (int t = 0; t < maxlen; ++t) {
    const int cur = t & 1;
    prefetch_x(t + 1);
    if (tid < SENTS) {
      int ll = len_s[tid], tt = t + 2;
      wid[tt & 1][tid] = (tt < ll) ? X[(g0 + tid) * 64 + (dir ? (ll - 1 - tt) : tt)] : 0;
    }

    bf16x8 a_hi[4], a_lo[4];
#pragma unroll
    for (int kk = 0; kk < 4; ++kk) {
      a_hi[kk] = *(const bf16x8*)&h_hi[li][32 * kk + 8 * g];
      a_lo[kk] = *(const bf16x8*)&h_lo[li][32 * kk + 8 * g];
    }
    f32x4 accg[4];
#pragma unroll
    for (int nt = 0; nt < 4; ++nt) {
      const int col = 64 * w + 16 * nt + li;
      f32x4 c;
#pragma unroll
      for (int r = 0; r < 4; ++r) c[r] = bgj[nt] + xbuf[cur][4 * g + r][col];
#pragma unroll
      for (int kk = 0; kk < 4; ++kk) {
        c = __builtin_amdgcn_mfma_f32_16x16x32_bf16(a_hi[kk], bgh[nt][kk], c, 0, 0, 0);
        c = __builtin_amdgcn_mfma_f32_16x16x32_bf16(a_hi[kk], bgl[nt][kk], c, 0, 0, 0);
        c = __builtin_amdgcn_mfma_f32_16x16x32_bf16(a_lo[kk], bgh[nt][kk], c, 0, 0, 0);
      }
      accg[nt] = c;
    }
    if (w < 2) {
#pragma unroll
      for (int nt = 0; nt < 4; ++nt) {
        const int col = 64 * w + 16 * nt + li;
#pragma unroll
        for (int r = 0; r < 4; ++r) {
          const int row = 4 * g + r;
          float s = sigm(accg[nt][r]);
          float rh = s * h_f[row][col];
          short hi, lo;
          split_bf16(rh, hi, lo);
          rh_hi[row][col] = hi;
          rh_lo[row][col] = lo;
        }
      }
    } else {
#pragma unroll
      for (int nt = 0; nt < 4; ++nt) {
        const int col = 64 * (w - 2) + 16 * nt + li;
#pragma unroll
        for (int r = 0; r < 4; ++r) {
          u_f[4 * g + r][col] = sigm(accg[nt][r]);
        }
      }
    }
    __syncthreads();

    bf16x8 ra_hi[4], ra_lo[4];
#pragma unroll
    for (int kk = 0; kk < 4; ++kk) {
      ra_hi[kk] = *(const bf16x8*)&rh_hi[li][32 * kk + 8 * g];
      ra_lo[kk] = *(const bf16x8*)&rh_lo[li][32 * kk + 8 * g];
    }
#pragma unroll
    for (int ct = 0; ct < 2; ++ct) {
      const int col = 32 * w + 16 * ct + li;
      f32x4 c;
#pragma unroll
      for (int r = 0; r < 4; ++r) c[r] = bcj[ct] + xbuf[cur][4 * g + r][256 + col];
#pragma unroll
      for (int kk = 0; kk < 4; ++kk) {
        c = __builtin_amdgcn_mfma_f32_16x16x32_bf16(ra_hi[kk], bch[ct][kk], c, 0, 0, 0);
        c = __builtin_amdgcn_mfma_f32_16x16x32_bf16(ra_hi[kk], bcl[ct][kk], c, 0, 0, 0);
        c = __builtin_amdgcn_mfma_f32_16x16x32_bf16(ra_lo[kk], bch[ct][kk], c, 0, 0, 0);
      }
#pragma unroll
      for (int r = 0; r < 4; ++r) {
        const int row = 4 * g + r;
        float cand = tanh_fast(c[r]);
        float u = u_f[row][col];
        float hold = h_f[row][col];
        float hn = u * hold + (1.f - u) * cand;
        hn = (t < lens4[r]) ? hn : hold;
        h_f[row][col] = hn;
        short hi, lo;
        split_bf16(hn, hi, lo);
        h_hi[row][col] = hi;
        h_lo[row][col] = lo;
      }
    }
    __syncthreads();
  }

  for (int q = tid; q < SENTS * 128; q += 256) {
    int m = q >> 7, j = q & 127;
    size_t o = (size_t)(g0 + m) * 256 + dir * 128 + j;
    sentHi[o] = h_hi[m][j];
    sentLo[o] = h_lo[m][j];
  }
}

// ---------------------------------------------------------------------------
// Doc GRU, f16 MFMA v4. grid (4, 2), block 512 = 8 waves. 16 docs/block.
// h carried as f16-hi only (single-pass A). x loads for step t+1 issued
// during step t into registers (latency hidden under MFMA+LDS work).
// Wave w: gate cols [64w,+64) (4 nt); cand cols [32w,+32) (2 ct).
// ---------------------------------------------------------------------------
#define DOCS 16

__global__ __launch_bounds__(512, 1) void doc_gru_mfma(
    const float* __restrict__ xprojD, const int* __restrict__ L2,
    const float* __restrict__ dWg_f, const float* __restrict__ dbg_f,
    const float* __restrict__ dWc_f, const float* __restrict__ dbc_f,
    const float* __restrict__ dWg_b, const float* __restrict__ dbg_b,
    const float* __restrict__ dWc_b, const float* __restrict__ dbc_b,
    float* __restrict__ docv) {
  const int dir = blockIdx.y;
  const int g0 = blockIdx.x * DOCS;
  const int tid = threadIdx.x;
  const int w = tid >> 6, l = tid & 63, li = l & 15, g = l >> 4;
  const float* Wg = dir ? dWg_b : dWg_f;   // [512,512], h rows 256..511
  const float* Wc = dir ? dWc_b : dWc_f;   // [512,256]
  const float* bgp = dir ? dbg_b : dbg_f;
  const float* bcp = dir ? dbc_b : dbc_f;
  const int xoff = dir ? 768 : 0;

  alignas(16) __shared__ short h_hi[DOCS][264];
  alignas(16) __shared__ short rh_hi[DOCS][264];
  __shared__ float h_f[DOCS][256], u_f[DOCS][256];
  __shared__ int len_s[DOCS];

  // ---- one-time: h-part weights (f16) into registers, pinned ----
  f16x8 wg[4][8];   // gates: [nt][kk], col = 64w+16nt+li, k = 32kk+8g+e
  f16x8 wc[2][8];   // cand:  [ct][kk], col = 32w+16ct+li
  const float* Wg_h = Wg + 256 * 512;
  const float* Wc_h = Wc + 256 * 256;
#pragma unroll
  for (int nt = 0; nt < 4; ++nt)
#pragma unroll
    for (int kk = 0; kk < 8; ++kk) {
      const float* base = Wg_h + (size_t)(32 * kk + 8 * g) * 512 + 64 * w + 16 * nt + li;
#pragma unroll
      for (int e = 0; e < 8; ++e) wg[nt][kk][e] = (_Float16)base[(size_t)e * 512];
      asm volatile("" : "+v"(wg[nt][kk]));
    }
#pragma unroll
  for (int ct = 0; ct < 2; ++ct)
#pragma unroll
    for (int kk = 0; kk < 8; ++kk) {
      const float* base = Wc_h + (size_t)(32 * kk + 8 * g) * 256 + 32 * w + 16 * ct + li;
#pragma unroll
      for (int e = 0; e < 8; ++e) wc[ct][kk][e] = (_Float16)base[(size_t)e * 256];
      asm volatile("" : "+v"(wc[ct][kk]));
    }
  float bgj[4], bcj[2];
#pragma unroll
  for (int nt = 0; nt < 4; ++nt) bgj[nt] = bgp[64 * w + 16 * nt + li];
#pragma unroll
  for (int ct = 0; ct < 2; ++ct) bcj[ct] = bcp[32 * w + 16 * ct + li];

  if (tid < DOCS) len_s[tid] = L2[g0 + tid];
  for (int q = tid; q < DOCS * 264; q += 512) ((short*)h_hi)[q] = 0;
  for (int q = tid; q < DOCS * 256; q += 512) {
    ((float*)h_f)[q] = 0.f; ((float*)u_f)[q] = 0.f;
  }
  __syncthreads();

  int lens4[4];
#pragma unroll
  for (int r = 0; r < 4; ++r) lens4[r] = len_s[4 * g + r];
  int maxlen = 0;
#pragma unroll
  for (int m = 0; m < DOCS; ++m) maxlen = max(maxlen, len_s[m]);

  // x row base for (doc-row r, step t); clamped so prefetch never goes OOB
  auto xrow = [&](int r, int t) -> size_t {
    int ti = dir ? max(lens4[r] - 1 - t, 0) : min(t, 31);
    return ((size_t)(g0 + 4 * g + r) * 32 + ti) * 1536 + xoff;
  };

  // ---- x register double-buffer: xg[16] gate cols, xc[8] cand cols ----
  float xg[16], xc[8], xgn[16], xcn[8];
#pragma unroll
  for (int r = 0; r < 4; ++r) {
    size_t xb = xrow(r, 0);
#pragma unroll
    for (int nt = 0; nt < 4; ++nt) xg[nt * 4 + r] = xprojD[xb + 64 * w + 16 * nt + li];
#pragma unroll
    for (int ct = 0; ct < 2; ++ct) xc[ct * 4 + r] = xprojD[xb + 512 + 32 * w + 16 * ct + li];
  }

  for (int t = 0; t < maxlen; ++t) {
    // accumulator init from current-x registers
    f32x4 acc[4];
#pragma unroll
    for (int nt = 0; nt < 4; ++nt)
#pragma unroll
      for (int r = 0; r < 4; ++r) acc[nt][r] = bgj[nt] + xg[nt * 4 + r];
    f32x4 acc2[2];
#pragma unroll
    for (int ct = 0; ct < 2; ++ct)
#pragma unroll
      for (int r = 0; r < 4; ++r) acc2[ct][r] = bcj[ct] + xc[ct * 4 + r];

    // issue next-step x loads; latency hides under this step's MFMA/LDS
#pragma unroll
    for (int r = 0; r < 4; ++r) {
      size_t xb = xrow(r, t + 1);
#pragma unroll
      for (int nt = 0; nt < 4; ++nt) xgn[nt * 4 + r] = xprojD[xb + 64 * w + 16 * nt + li];
#pragma unroll
      for (int ct = 0; ct < 2; ++ct) xcn[ct * 4 + r] = xprojD[xb + 512 + 32 * w + 16 * ct + li];
    }

    // ---- gates: 8 k-chunks, single-pass f16 ----
#pragma unroll
    for (int c = 0; c < 8; ++c) {
      f16x8 ah = *(const f16x8*)&h_hi[li][32 * c + 8 * g];
#pragma unroll
      for (int nt = 0; nt < 4; ++nt)
        acc[nt] = __builtin_amdgcn_mfma_f32_16x16x32_f16(ah, wg[nt][c], acc[nt], 0, 0, 0);
    }
    if (w < 4) {               // r-gate columns -> rh (f16)
#pragma unroll
      for (int nt = 0; nt < 4; ++nt) {
        const int col = 64 * w + 16 * nt + li;
#pragma unroll
        for (int r = 0; r < 4; ++r) {
          const int m = 4 * g + r;
          float s = sigm(acc[nt][r]);
          float rh = s * h_f[m][col];
          rh_hi[m][col] = __builtin_bit_cast(short, (_Float16)rh);
        }
      }
    } else {                   // u-gate columns
#pragma unroll
      for (int nt = 0; nt < 4; ++nt) {
        const int col = 64 * (w - 4) + 16 * nt + li;
#pragma unroll
        for (int r = 0; r < 4; ++r) u_f[4 * g + r][col] = sigm(acc[nt][r]);
      }
    }
    __syncthreads();

    // ---- candidate: 8 k-chunks over rh, single-pass ----
#pragma unroll
    for (int c = 0; c < 8; ++c) {
      f16x8 rah = *(const f16x8*)&rh_hi[li][32 * c + 8 * g];
#pragma unroll
      for (int ct = 0; ct < 2; ++ct)
        acc2[ct] = __builtin_amdgcn_mfma_f32_16x16x32_f16(rah, wc[ct][c], acc2[ct], 0, 0, 0);
    }
#pragma unroll
    for (int ct = 0; ct < 2; ++ct) {
      const int col = 32 * w + 16 * ct + li;
#pragma unroll
      for (int r = 0; r < 4; ++r) {
        const int m = 4 * g + r;
        float cand = tanh_fast(acc2[ct][r]);
        float u = u_f[m][col];
        float hold = h_f[m][col];
        float hn = u * hold + (1.f - u) * cand;
        hn = (t < lens4[r]) ? hn : hold;
        h_f[m][col] = hn;
        h_hi[m][col] = __builtin_bit_cast(short, (_Float16)hn);
      }
    }
    __syncthreads();

    // rotate x double-buffer (register moves)
#pragma unroll
    for (int i = 0; i < 16; ++i) xg[i] = xgn[i];
#pragma unroll
    for (int i = 0; i < 8; ++i) xc[i] = xcn[i];
  }

  for (int q = tid; q < DOCS * 256; q += 512) {
    int m = q >> 8, j = q & 255;
    docv[(size_t)(g0 + m) * 512 + dir * 256 + j] = h_f[m][j];
  }
}

__global__ __launch_bounds__(256) void mlp_head(
    const float* __restrict__ docv, const float* __restrict__ W1,
    const float* __restrict__ b1, const float* __restrict__ W2,
    const float* __restrict__ b2, float* __restrict__ out) {
  const int b = blockIdx.x, j = threadIdx.x;
  __shared__ float hid[256];
  float acc = b1[j];
#pragma unroll 4
  for (int k = 0; k < 512; ++k) acc += docv[b * 512 + k] * W1[k * 256 + j];
  hid[j] = fmaxf(acc, 0.f);
  __syncthreads();
  if (j < 5) {
    float a = b2[j];
#pragma unroll 4
    for (int k = 0; k < 256; ++k) a += hid[k] * W2[k * 5 + j];
    out[b * 5 + j] = a;
  }
}

extern "C" void kernel_launch(void* const* d_in, const int* in_sizes, int n_in,
                              void* d_out, int out_size, void* d_ws, size_t ws_size,
                              hipStream_t stream) {
  const int* X = (const int*)d_in[0];
  const int* L = (const int*)d_in[1];
  const int* L2 = (const int*)d_in[2];
  const float* emb = (const float*)d_in[3];
  const float* sWg_f = (const float*)d_in[4];
  const float* sbg_f = (const float*)d_in[5];
  const float* sWc_f = (const float*)d_in[6];
  const float* sbc_f = (const float*)d_in[7];
  const float* sWg_b = (const float*)d_in[8];
  const float* sbg_b = (const float*)d_in[9];
  const float* sWc_b = (const float*)d_in[10];
  const float* sbc_b = (const float*)d_in[11];
  const float* dWg_f = (const float*)d_in[12];
  const float* dbg_f = (const float*)d_in[13];
  const float* dWc_f = (const float*)d_in[14];
  const float* dbc_f = (const float*)d_in[15];
  const float* dWg_b = (const float*)d_in[16];
  const float* dbg_b = (const float*)d_in[17];
  const float* dWc_b = (const float*)d_in[18];
  const float* dbc_b = (const float*)d_in[19];
  const float* W1 = (const float*)d_in[20];
  const float* b1 = (const float*)d_in[21];
  const float* W2 = (const float*)d_in[22];
  const float* b2 = (const float*)d_in[23];
  float* out = (float*)d_out;

  float* ws = (float*)d_ws;
  float* embProj = ws;                        // 50000*768 f32
  float* xprojD = embProj + 38400000;         // 2048*1536 f32
  float* docv = xprojD + 3145728;             // 64*512 f32
  short* sentHi = (short*)(docv + 32768);     // 2048*256 bf16
  short* sentLo = sentHi + 524288;
  short* BtHi = sentLo + 524288;              // 768*128 bf16
  short* BtLo = BtHi + 98304;
  short* PdTHi = BtLo + 98304;                // 1536*256 bf16
  short* PdTLo = PdTHi + 393216;

  // weight prep
  hipLaunchKernelGGL(bt_prep, dim3(384), dim3(256), 0, stream,
                     sWg_f, sWc_f, sWg_b, sWc_b, BtHi, BtLo);
  hipLaunchKernelGGL(packdt_prep, dim3(1536), dim3(256), 0, stream,
                     dWg_f, dWc_f, dWg_b, dWc_b, PdTHi, PdTLo);

  // embProj = emb @ packS  [50000,768] (MFMA split-bf16)
  hipLaunchKernelGGL(emb_gemm, dim3(782), dim3(256), 0, stream,
                     emb, BtHi, BtLo, embProj);

  // sentence bi-GRU -> sentHi/sentLo [2048,256] bf16 planes
  hipLaunchKernelGGL(sent_gru, dim3(128, 2), dim3(256), 0, stream,
                     X, L, embProj,
                     sWg_f, sbg_f, sWc_f, sbc_f,
                     sWg_b, sbg_b, sWc_b, sbc_b, sentHi, sentLo);

  // xprojD = sent @ packD  [2048,1536] (MFMA split-bf16)
  hipLaunchKernelGGL(xproj_gemm, dim3(32, 3), dim3(256), 0, stream,
                     sentHi, sentLo, PdTHi, PdTLo, xprojD);

  // doc bi-GRU -> docv [64,512]
  hipLaunchKernelGGL(doc_gru_mfma, dim3(4, 2), dim3(512), 0, stream,
                     xprojD, L2,
                     dWg_f, dbg_f, dWc_f, dbc_f,
                     dWg_b, dbg_b, dWc_b, dbc_b, docv);

  hipLaunchKernelGGL(mlp_head, dim3(64), dim3(256), 0, stream,
                     docv, W1, b1, W2, b2, out);
}